// Round 3
// baseline (312.854 us; speedup 1.0000x reference)
//
#include <hip/hip_runtime.h>
#include <hip/hip_bf16.h>

#define B_  8
#define N_  2048
#define KD_ 256
#define AD_ 128
#define VD_ 256

using s16x8 = __attribute__((ext_vector_type(8))) short;
using f16x8 = __attribute__((ext_vector_type(8))) _Float16;
using h2    = __attribute__((ext_vector_type(2))) __fp16;
using f32x4 = __attribute__((ext_vector_type(4))) float;

__device__ __forceinline__ f32x4 mfma16(s16x8 a, s16x8 b, f32x4 c) {
  return __builtin_amdgcn_mfma_f32_16x16x32_f16(
      __builtin_bit_cast(f16x8, a), __builtin_bit_cast(f16x8, b), c, 0, 0, 0);
}
__device__ __forceinline__ short f2h(float f) {
  _Float16 h = (_Float16)f;
  return *reinterpret_cast<short*>(&h);
}
// 8 consecutive fp32 -> f16x8 via packed cvt
__device__ __forceinline__ s16x8 cvt8(const float* __restrict__ p) {
  union { s16x8 v; h2 h[4]; } u;
  f32x4 a = *(const f32x4*)p;
  f32x4 bq = *(const f32x4*)(p + 4);
  u.h[0] = __builtin_amdgcn_cvt_pkrtz(a[0], a[1]);
  u.h[1] = __builtin_amdgcn_cvt_pkrtz(a[2], a[3]);
  u.h[2] = __builtin_amdgcn_cvt_pkrtz(bq[0], bq[1]);
  u.h[3] = __builtin_amdgcn_cvt_pkrtz(bq[2], bq[3]);
  return u.v;
}

// ---------------- W transpose+convert: WT[n][k] = f16(W[k][n]) --------------
__global__ void transW_k(const float* __restrict__ W1, const float* __restrict__ W2,
                         short* __restrict__ WT1, short* __restrict__ WT2) {
  const float* W = blockIdx.x ? W2 : W1;
  short* WT      = blockIdx.x ? WT2 : WT1;
  for (int i = threadIdx.x; i < KD_ * AD_; i += blockDim.x) {
    int k = i >> 7, n = i & 127;
    WT[n * KD_ + k] = f2h(W[i]);
  }
}

// ---------------- V transpose+convert, B-frag-major -------------------------
// vt[b][kt] region (16384 f16): [(w*8 + vchunk*2 + ks2)*64 + quad*16 + l16]*8+j
// holds V[key = ks2*32 + quad*8 + j][v = w*64 + vchunk*16 + l16].
__global__ __launch_bounds__(256) void transV_k(
    const float* __restrict__ v1, const float* __restrict__ v2,
    short* __restrict__ vt1, short* __restrict__ vt2) {
  const int t  = threadIdx.x;           // = v index (0..255)
  const int kt = blockIdx.x;
  const int b  = blockIdx.y;
  const float* src = blockIdx.z ? v2 : v1;
  short*       dst = blockIdx.z ? vt2 : vt1;
  const size_t base = ((size_t)(b * 32 + kt)) * (256 * 64);
  const int w = t >> 6, vchunk = (t >> 4) & 3, l16 = t & 15;
  #pragma unroll
  for (int i = 0; i < 8; i++) {         // key-chunk of 8
    float x[8];
    #pragma unroll
    for (int kk = 0; kk < 8; kk++)
      x[kk] = src[((size_t)(b * N_ + kt * 64 + i * 8 + kk)) * VD_ + t];
    union { s16x8 v; h2 h[4]; } u;
    #pragma unroll
    for (int kk = 0; kk < 4; kk++)
      u.h[kk] = __builtin_amdgcn_cvt_pkrtz(x[2 * kk], x[2 * kk + 1]);
    int f = vchunk * 2 + (i >> 2);      // ks2 = i>>2, quad = i&3
    *(s16x8*)&dst[base + (size_t)((w * 8 + f) * 64 + (i & 3) * 16 + l16) * 8] = u.v;
  }
}

// ---------------- projection: Y[m][n] = f16(X@W + bias) ---------------------
__global__ __launch_bounds__(256, 2) void proj_k(
    const float* __restrict__ X, const short* __restrict__ WT,
    const float* __restrict__ bias, short* __restrict__ Y) {
  __shared__ __align__(16) short sA[64 * 264];
  const int t    = threadIdx.x;
  const int m0   = blockIdx.x * 64;
  const int lane = t & 63, wave = t >> 6, quad = lane >> 4, l16 = lane & 15;
  #pragma unroll
  for (int i = 0; i < 8; i++) {
    int chunk = i * 256 + t, row = chunk >> 5, c8 = chunk & 31;
    *(s16x8*)&sA[row * 264 + c8 * 8] =
        cvt8(&X[((size_t)(m0 + row)) * KD_ + c8 * 8]);
  }
  __syncthreads();
  f32x4 acc[8];
  #pragma unroll
  for (int nt = 0; nt < 8; nt++) acc[nt] = (f32x4){0.f, 0.f, 0.f, 0.f};
  #pragma unroll
  for (int ks = 0; ks < 8; ks++) {
    s16x8 a = *(const s16x8*)&sA[(wave * 16 + l16) * 264 + ks * 32 + quad * 8];
    #pragma unroll
    for (int nt = 0; nt < 8; nt++) {
      s16x8 bf = *(const s16x8*)&WT[(nt * 16 + l16) * KD_ + ks * 32 + quad * 8];
      acc[nt] = mfma16(a, bf, acc[nt]);
    }
  }
  #pragma unroll
  for (int nt = 0; nt < 8; nt++) {
    float bv = bias[nt * 16 + l16];
    #pragma unroll
    for (int r = 0; r < 4; r++) {
      int row = m0 + wave * 16 + quad * 4 + r;
      Y[(size_t)row * AD_ + nt * 16 + l16] = f2h(acc[nt][r] + bv);
    }
  }
}

// ---------------- flash attention, no K LDS staging -------------------------
// QK^T q-split across waves (swapped operands -> in-lane softmax); K A-frags
// load directly from global (L1/L2-hot, half prefetched during prior PV).
// PV v-split across waves: P via LDS sP, V streamed to registers.
// Grid: 1-D 512, XCD-swizzled so each XCD owns 2 (b,pass) pairs (~4MB = L2).
__global__ __launch_bounds__(256, 2) void attn_k(
    const short* __restrict__ q1p, const short* __restrict__ q2p,
    const short* __restrict__ vt1, const short* __restrict__ vt2,
    float* __restrict__ out) {
  __shared__ __align__(16) short sP[2][4][16 * 64];  // 16384 B, XOR-swizzled
  __shared__ __align__(16) float sAl[2][68];         // alpha[64] + flags[4]

  const int t    = threadIdx.x;
  const int lane = t & 63, wave = t >> 6, quad = lane >> 4, l16 = lane & 15;
  // XCD-aware decode: xcd = id&7 (round-robin dispatch); each XCD gets
  // bp in {2*xcd, 2*xcd+1}; consecutive blocks share bp for L1 reuse.
  const int id   = blockIdx.x;
  const int xcd  = id & 7, seq = id >> 3;
  const int bp   = xcd * 2 + (seq >> 5);
  const int qb   = seq & 31;
  const int b    = bp & 7, pass = bp >> 3;
  const int q0   = qb * 64;
  const short* Q  = pass ? q2p : q1p;
  const short* K  = pass ? q1p : q2p;
  const short* Vt = pass ? vt1 : vt2;
  float* O = out + (size_t)pass * ((size_t)B_ * N_ * VD_);
  const size_t vbase0 = (size_t)b * 32 * (256 * 64);
  const size_t kbase  = (size_t)(b * N_) * AD_;

  // Q fragments direct from global (A/B-frag layout), loop-invariant
  s16x8 qf[4];
  #pragma unroll
  for (int ks = 0; ks < 4; ks++)
    qf[ks] = *(const s16x8*)&Q[((size_t)(b * N_ + q0 + wave * 16 + l16)) * AD_ +
                               ks * 32 + quad * 8];

  float m_i = -1e30f, l_i = 0.f;
  f32x4 acc[16];
  #pragma unroll
  for (int c0 = 0; c0 < 16; c0++) acc[c0] = (f32x4){0.f, 0.f, 0.f, 0.f};

  s16x8 pv[8], kfa[8];
  auto loadKfa = [&](int kt) {          // ks = 0,1 half of next K tile
    #pragma unroll
    for (int x = 0; x < 8; x++) {
      int ks = x >> 2, nt = x & 3;
      kfa[x] = *(const s16x8*)&K[kbase +
          (size_t)(kt * 64 + nt * 16 + l16) * AD_ + ks * 32 + quad * 8];
    }
  };
  auto loadV = [&](int kt) {
    const size_t vb = vbase0 + (size_t)kt * (256 * 64) + (size_t)wave * 4096;
    #pragma unroll
    for (int f = 0; f < 8; f++)
      pv[f] = *(const s16x8*)&Vt[vb + (size_t)(f * 64 + lane) * 8];
  };

  // prologue
  loadV(0);
  loadKfa(0);

  int c = 0;
  for (int kt = 0; kt < 32; kt++) {
    // ks = 2,3 half straight from global (hidden under kfa MFMAs)
    s16x8 kfb[8];
    #pragma unroll
    for (int x = 0; x < 8; x++) {
      int ks = 2 + (x >> 2), nt = x & 3;
      kfb[x] = *(const s16x8*)&K[kbase +
          (size_t)(kt * 64 + nt * 16 + l16) * AD_ + ks * 32 + quad * 8];
    }

    // S^T = K Q^T : st[nt] = S[key = nt*16+quad*4+r][q = wave*16 + l16]
    f32x4 st[4];
    #pragma unroll
    for (int nt = 0; nt < 4; nt++) st[nt] = (f32x4){0.f, 0.f, 0.f, 0.f};
    __builtin_amdgcn_s_setprio(1);
    #pragma unroll
    for (int x = 0; x < 8; x++)
      st[x & 3] = mfma16(kfa[x], qf[x >> 2], st[x & 3]);
    #pragma unroll
    for (int x = 0; x < 8; x++)
      st[x & 3] = mfma16(kfb[x], qf[2 + (x >> 2)], st[x & 3]);
    __builtin_amdgcn_s_setprio(0);

    // in-lane tile max (16 vals) + quad combine
    float mt = st[0][0];
    #pragma unroll
    for (int nt = 0; nt < 4; nt++) {
      #pragma unroll
      for (int r = 0; r < 4; r++) mt = fmaxf(mt, st[nt][r]);
    }
    mt = fmaxf(mt, __shfl_xor(mt, 16));
    mt = fmaxf(mt, __shfl_xor(mt, 32));

    // defer-max: rescale only when tile max grew by > 8 (P <= e^8 fits f16)
    float alpha = 1.f;
    bool  resc  = !__all(mt - m_i <= 8.f);
    if (resc) {
      float mn = fmaxf(m_i, mt);
      alpha = __expf(m_i - mn);
      l_i *= alpha;
      m_i  = mn;
    }

    // p = exp(s - m_i); in-lane partial sums + quad combine
    f32x4 psv = (f32x4){0.f, 0.f, 0.f, 0.f};
    #pragma unroll
    for (int nt = 0; nt < 4; nt++) {
      #pragma unroll
      for (int r = 0; r < 4; r++) {
        float p = __expf(st[nt][r] - m_i);
        st[nt][r] = p;
        psv[r] += p;
      }
    }
    float sum = (psv[0] + psv[1]) + (psv[2] + psv[3]);
    sum += __shfl_xor(sum, 16);
    sum += __shfl_xor(sum, 32);
    l_i += sum;

    // pack P pairs -> 8B swizzled writes into shared sP[c][wave]
    #pragma unroll
    for (int nt = 0; nt < 4; nt++) {
      union { h2 h[2]; uint2 u; } wu;
      wu.h[0] = __builtin_amdgcn_cvt_pkrtz(st[nt][0], st[nt][1]);
      wu.h[1] = __builtin_amdgcn_cvt_pkrtz(st[nt][2], st[nt][3]);
      int cp = (nt * 4 + quad) ^ ((l16 & 7) << 1);
      *(uint2*)&sP[c][wave][l16 * 64 + cp * 4] = wu.u;
    }
    // publish rescale factors (alpha uniform across quads)
    if (quad == 0) sAl[c][wave * 16 + l16] = alpha;
    if (lane == 0) sAl[c][64 + wave] = resc ? 1.f : 0.f;

    __syncthreads();

    // prefetch ks=0,1 K half for next tile (in flight across PV, no barrier)
    if (kt + 1 < 32) loadKfa(kt + 1);

    // cross-wave acc rescale (rare: flag word is a broadcast read)
    f32x4 fl = *(const f32x4*)&sAl[c][64];
    if (fl[0] + fl[1] + fl[2] + fl[3] != 0.f) {
      #pragma unroll
      for (int m = 0; m < 4; m++) {
        f32x4 aR = *(const f32x4*)&sAl[c][m * 16 + quad * 4];
        #pragma unroll
        for (int v = 0; v < 4; v++) {
          #pragma unroll
          for (int r = 0; r < 4; r++) acc[m * 4 + v][r] *= aR[r];
        }
      }
    }

    // O[q][v-slice of this wave] += P @ V   (af: LDS broadcast; bf: registers)
    __builtin_amdgcn_s_setprio(1);
    #pragma unroll
    for (int m = 0; m < 4; m++) {
      #pragma unroll
      for (int ks2 = 0; ks2 < 2; ks2++) {
        int cp = (ks2 * 8 + quad * 2) ^ ((l16 & 7) << 1);
        s16x8 af = *(const s16x8*)&sP[c][m][l16 * 64 + cp * 4];
        #pragma unroll
        for (int v = 0; v < 4; v++)
          acc[m * 4 + v] = mfma16(af, pv[v * 2 + ks2], acc[m * 4 + v]);
      }
    }
    __builtin_amdgcn_s_setprio(0);

    // stream next V tile into registers (consumed after next barrier)
    if (kt + 1 < 32) loadV(kt + 1);
    c ^= 1;
  }

  // epilogue: share l_i across waves (q-row wave*16+l16 -> all waves need it)
  if (quad == 0) sAl[0][wave * 16 + l16] = l_i;
  __syncthreads();
  #pragma unroll
  for (int m = 0; m < 4; m++) {
    f32x4 lv = *(const f32x4*)&sAl[0][m * 16 + quad * 4];
    #pragma unroll
    for (int r = 0; r < 4; r++) {
      float inv = 1.f / lv[r];
      int row = q0 + m * 16 + quad * 4 + r;
      #pragma unroll
      for (int v = 0; v < 4; v++)
        O[((size_t)(b * N_ + row)) * VD_ + wave * 64 + v * 16 + l16] =
            acc[m * 4 + v][r] * inv;
    }
  }
}

extern "C" void kernel_launch(void* const* d_in, const int* in_sizes, int n_in,
                              void* d_out, int out_size, void* d_ws, size_t ws_size,
                              hipStream_t stream) {
  const float* k1 = (const float*)d_in[0];
  const float* k2 = (const float*)d_in[1];
  const float* v1 = (const float*)d_in[2];
  const float* v2 = (const float*)d_in[3];
  const float* W1 = (const float*)d_in[4];
  const float* b1 = (const float*)d_in[5];
  const float* W2 = (const float*)d_in[6];
  const float* b2 = (const float*)d_in[7];

  short* ws  = (short*)d_ws;
  short* q1p = ws;                                   // 16384*128 f16 (4 MB)
  short* q2p = q1p + (size_t)16384 * 128;
  short* wt1 = q2p + (size_t)16384 * 128;            // 128*256 f16
  short* wt2 = wt1 + (size_t)128 * 256;
  short* vt1 = wt2 + (size_t)128 * 256;              // 8*32*256*64 f16 (8.4 MB)
  short* vt2 = vt1 + (size_t)B_ * 32 * 256 * 64;
  float* out = (float*)d_out;

  transW_k<<<dim3(2), dim3(256), 0, stream>>>(W1, W2, wt1, wt2);
  transV_k<<<dim3(32, 8, 2), dim3(256), 0, stream>>>(v1, v2, vt1, vt2);
  proj_k<<<dim3(256), dim3(256), 0, stream>>>(k1, wt1, b1, q1p);
  proj_k<<<dim3(256), dim3(256), 0, stream>>>(k2, wt2, b2, q2p);
  attn_k<<<dim3(512), dim3(256), 0, stream>>>(q1p, q2p, vt1, vt2, out);
}

// Round 4
// 181.567 us; speedup vs baseline: 1.7231x; 1.7231x over previous
//
#include <hip/hip_runtime.h>
#include <hip/hip_bf16.h>

#define B_  8
#define N_  2048
#define KD_ 256
#define AD_ 128
#define VD_ 256

using s16x8 = __attribute__((ext_vector_type(8))) short;
using f16x8 = __attribute__((ext_vector_type(8))) _Float16;
using h2    = __attribute__((ext_vector_type(2))) __fp16;
using f32x4 = __attribute__((ext_vector_type(4))) float;

__device__ __forceinline__ f32x4 mfma16(s16x8 a, s16x8 b, f32x4 c) {
  return __builtin_amdgcn_mfma_f32_16x16x32_f16(
      __builtin_bit_cast(f16x8, a), __builtin_bit_cast(f16x8, b), c, 0, 0, 0);
}
// 8 consecutive fp32 -> f16x8 via packed cvt
__device__ __forceinline__ s16x8 cvt8(const float* __restrict__ p) {
  union { s16x8 v; h2 h[4]; } u;
  f32x4 a = *(const f32x4*)p;
  f32x4 bq = *(const f32x4*)(p + 4);
  u.h[0] = __builtin_amdgcn_cvt_pkrtz(a[0], a[1]);
  u.h[1] = __builtin_amdgcn_cvt_pkrtz(a[2], a[3]);
  u.h[2] = __builtin_amdgcn_cvt_pkrtz(bq[0], bq[1]);
  u.h[3] = __builtin_amdgcn_cvt_pkrtz(bq[2], bq[3]);
  return u.v;
}

// ---------------- fused prep ------------------------------------------------
// blocks [0,512): transV role  -> vt (B-frag-major f16)
// blocks [512,1024): proj role -> q1p/q2p = f16(X@W + bias); W^T staged in LDS
__global__ __launch_bounds__(256) void prep_k(
    const float* __restrict__ k1, const float* __restrict__ k2,
    const float* __restrict__ v1, const float* __restrict__ v2,
    const float* __restrict__ W1, const float* __restrict__ b1f,
    const float* __restrict__ W2, const float* __restrict__ b2f,
    short* __restrict__ q1p, short* __restrict__ q2p,
    short* __restrict__ vt1, short* __restrict__ vt2) {
  __shared__ __align__(16) short sWT[128 * 264];   // 67584 B (proj role only)
  const int t  = threadIdx.x;
  const int id = blockIdx.x;

  if (id < 512) {
    // ---- transV: vt[b][kt] frag-major:
    // [(w*8 + vchunk*2 + ks2)*64 + quad*16 + l16]*8 + j  holds
    // V[key = ks2*32 + quad*8 + j][v = w*64 + vchunk*16 + l16]
    const int kt = id & 31, b = (id >> 5) & 7, z = id >> 8;
    const float* src = z ? v2 : v1;
    short*       dst = z ? vt2 : vt1;
    const size_t base = ((size_t)(b * 32 + kt)) * (256 * 64);
    const int w = t >> 6, vchunk = (t >> 4) & 3, l16 = t & 15;
    #pragma unroll
    for (int i = 0; i < 8; i++) {       // key-chunk of 8
      float x[8];
      #pragma unroll
      for (int kk = 0; kk < 8; kk++)
        x[kk] = src[((size_t)(b * N_ + kt * 64 + i * 8 + kk)) * VD_ + t];
      union { s16x8 v; h2 h[4]; } u;
      #pragma unroll
      for (int kk = 0; kk < 4; kk++)
        u.h[kk] = __builtin_amdgcn_cvt_pkrtz(x[2 * kk], x[2 * kk + 1]);
      int f = vchunk * 2 + (i >> 2);    // ks2 = i>>2, quad' = i&3
      *(s16x8*)&dst[base + (size_t)((w * 8 + f) * 64 + (i & 3) * 16 + l16) * 8] = u.v;
    }
    return;
  }

  // ---- proj ----
  const int pid = id - 512;
  const int z = pid >> 8, mb = pid & 255;
  const float* X    = z ? k2 : k1;
  const float* W    = z ? W2 : W1;
  const float* bias = z ? b2f : b1f;
  short*       Y    = z ? q2p : q1p;
  const int m0   = mb * 64;
  const int lane = t & 63, wave = t >> 6, quad = lane >> 4, l16 = lane & 15;

  // stage W^T f16 into LDS: sWT[n*264 + k]; pack k-pairs -> u32 writes
  #pragma unroll
  for (int j = 0; j < 64; j++) {
    int idx = j * 256 + t;              // pair index
    int n = idx & 127, kh = idx >> 7;   // k = 2*kh, 2*kh+1
    h2 p = __builtin_amdgcn_cvt_pkrtz(W[(size_t)(2 * kh) * AD_ + n],
                                      W[(size_t)(2 * kh + 1) * AD_ + n]);
    *(h2*)&sWT[n * 264 + kh * 2] = p;
  }
  // A-frags direct from global (one X row per thread)
  const float* xrow = &X[(size_t)(m0 + wave * 16 + l16) * KD_];
  s16x8 a[8];
  #pragma unroll
  for (int ks = 0; ks < 8; ks++) a[ks] = cvt8(xrow + ks * 32 + quad * 8);
  __syncthreads();

  f32x4 acc[8];
  #pragma unroll
  for (int nt = 0; nt < 8; nt++) acc[nt] = (f32x4){0.f, 0.f, 0.f, 0.f};
  #pragma unroll
  for (int ks = 0; ks < 8; ks++) {
    #pragma unroll
    for (int nt = 0; nt < 8; nt++) {
      s16x8 bf = *(const s16x8*)&sWT[(nt * 16 + l16) * 264 + ks * 32 + quad * 8];
      acc[nt] = mfma16(a[ks], bf, acc[nt]);
    }
  }
  #pragma unroll
  for (int nt = 0; nt < 8; nt++) {
    float bv = bias[nt * 16 + l16];
    #pragma unroll
    for (int r = 0; r < 4; r++) {
      int row = m0 + wave * 16 + quad * 4 + r;
      _Float16 h = (_Float16)(acc[nt][r] + bv);
      Y[(size_t)row * AD_ + nt * 16 + l16] = *reinterpret_cast<short*>(&h);
    }
  }
}

// ---------------- flash attention (R2 structure + XCD swizzle) --------------
// QK^T q-split across waves, swapped operands -> in-lane softmax; K tile
// double-buffered in LDS (reg-prefetched); PV v-split, P via LDS, V in regs.
// Grid 1-D 512, XCD-swizzled: each XCD owns 2 (b,pass) pairs (~4MB = its L2).
__global__ __launch_bounds__(256, 2) void attn_k(
    const short* __restrict__ q1p, const short* __restrict__ q2p,
    const short* __restrict__ vt1, const short* __restrict__ vt2,
    float* __restrict__ out) {
  __shared__ __align__(16) short sK[2][64 * 136];    // 34816 B
  __shared__ __align__(16) short sP[2][4][16 * 64];  // 16384 B, XOR-swizzled
  __shared__ __align__(16) float sAl[2][68];         // alpha[64] + flags[4]

  const int t    = threadIdx.x;
  const int lane = t & 63, wave = t >> 6, quad = lane >> 4, l16 = lane & 15;
  // XCD-aware decode (512 % 8 == 0 -> bijective): xcd = id&7 round-robin.
  const int id   = blockIdx.x;
  const int xcd  = id & 7, seq = id >> 3;
  const int bp   = xcd * 2 + (seq >> 5);
  const int qb   = seq & 31;
  const int b    = bp & 7, pass = bp >> 3;
  const int q0   = qb * 64;
  const short* Q  = pass ? q2p : q1p;
  const short* K  = pass ? q1p : q2p;
  const short* Vt = pass ? vt1 : vt2;
  float* O = out + (size_t)pass * ((size_t)B_ * N_ * VD_);

  // strength-reduced pointers: per-lane base once, uniform advance per tile
  const short* kp = K + (size_t)(b * N_) * AD_ + (size_t)(t >> 4) * AD_ + (t & 15) * 8;
  const short* vp = Vt + (size_t)b * 32 * (256 * 64) + wave * 4096 + lane * 8;

  // Q fragments direct from global, loop-invariant
  s16x8 qf[4];
  #pragma unroll
  for (int ks = 0; ks < 4; ks++)
    qf[ks] = *(const s16x8*)&Q[((size_t)(b * N_ + q0 + wave * 16 + l16)) * AD_ +
                               ks * 32 + quad * 8];

  float m_i = -1e30f, l_i = 0.f;
  f32x4 acc[16];
  #pragma unroll
  for (int c0 = 0; c0 < 16; c0++) acc[c0] = (f32x4){0.f, 0.f, 0.f, 0.f};

  s16x8 pk[4], pv[8];
  auto loadK = [&]() {
    #pragma unroll
    for (int i = 0; i < 4; i++)
      pk[i] = *(const s16x8*)(kp + i * 16 * AD_);
    kp += 64 * AD_;
  };
  auto loadV = [&]() {
    #pragma unroll
    for (int f = 0; f < 8; f++)
      pv[f] = *(const s16x8*)(vp + f * 512);
    vp += 256 * 64;
  };
  auto storeK = [&](int cb) {
    #pragma unroll
    for (int i = 0; i < 4; i++) {
      int chunk = i * 256 + t, row = chunk >> 4, c8 = chunk & 15;
      *(s16x8*)&sK[cb][row * 136 + c8 * 8] = pk[i];
    }
  };

  // prologue: sK[0] <- K(0); pk <- K(1); pv <- V(0)
  loadK();
  storeK(0);
  loadK();
  loadV();
  __syncthreads();

  int c = 0;
  for (int kt = 0; kt < 32; kt++) {
    // S^T = K Q^T : st[nt] = S[key = nt*16+quad*4+r][q = wave*16 + l16]
    f32x4 st[4];
    #pragma unroll
    for (int nt = 0; nt < 4; nt++) st[nt] = (f32x4){0.f, 0.f, 0.f, 0.f};
    __builtin_amdgcn_s_setprio(1);
    #pragma unroll
    for (int ks = 0; ks < 4; ks++) {
      #pragma unroll
      for (int nt = 0; nt < 4; nt++) {
        s16x8 kf = *(const s16x8*)&sK[c][(nt * 16 + l16) * 136 + ks * 32 + quad * 8];
        st[nt] = mfma16(kf, qf[ks], st[nt]);
      }
    }
    __builtin_amdgcn_s_setprio(0);

    // in-lane tile max (16 vals) + quad combine
    float mt = st[0][0];
    #pragma unroll
    for (int nt = 0; nt < 4; nt++) {
      #pragma unroll
      for (int r = 0; r < 4; r++) mt = fmaxf(mt, st[nt][r]);
    }
    mt = fmaxf(mt, __shfl_xor(mt, 16));
    mt = fmaxf(mt, __shfl_xor(mt, 32));

    // defer-max: rescale only when tile max grew by > 8 (P <= e^8 fits f16)
    float alpha = 1.f;
    bool  resc  = !__all(mt - m_i <= 8.f);
    if (resc) {
      float mn = fmaxf(m_i, mt);
      alpha = __expf(m_i - mn);
      l_i *= alpha;
      m_i  = mn;
    }

    // p = exp(s - m_i); in-lane partial sums + quad combine
    f32x4 psv = (f32x4){0.f, 0.f, 0.f, 0.f};
    #pragma unroll
    for (int nt = 0; nt < 4; nt++) {
      #pragma unroll
      for (int r = 0; r < 4; r++) {
        float p = __expf(st[nt][r] - m_i);
        st[nt][r] = p;
        psv[r] += p;
      }
    }
    float sum = (psv[0] + psv[1]) + (psv[2] + psv[3]);
    sum += __shfl_xor(sum, 16);
    sum += __shfl_xor(sum, 32);
    l_i += sum;

    // pack P pairs -> 8B swizzled writes into shared sP[c][wave]
    #pragma unroll
    for (int nt = 0; nt < 4; nt++) {
      union { h2 h[2]; uint2 u; } wu;
      wu.h[0] = __builtin_amdgcn_cvt_pkrtz(st[nt][0], st[nt][1]);
      wu.h[1] = __builtin_amdgcn_cvt_pkrtz(st[nt][2], st[nt][3]);
      int cp = (nt * 4 + quad) ^ ((l16 & 7) << 1);
      *(uint2*)&sP[c][wave][l16 * 64 + cp * 4] = wu.u;
    }
    // publish rescale factors (alpha uniform across quads)
    if (quad == 0) sAl[c][wave * 16 + l16] = alpha;
    if (lane == 0) sAl[c][64 + wave] = resc ? 1.f : 0.f;

    // commit next K tile into the other buffer (pk already in regs)
    if (kt + 1 < 32) storeK(1 - c);

    __syncthreads();

    // prefetch K(kt+2) AFTER the barrier so the drain never waits on it
    if (kt + 2 < 32) loadK();

    // cross-wave acc rescale (rare: flag word is a broadcast read)
    f32x4 fl = *(const f32x4*)&sAl[c][64];
    if (fl[0] + fl[1] + fl[2] + fl[3] != 0.f) {
      #pragma unroll
      for (int m = 0; m < 4; m++) {
        f32x4 aR = *(const f32x4*)&sAl[c][m * 16 + quad * 4];
        #pragma unroll
        for (int v = 0; v < 4; v++) {
          #pragma unroll
          for (int r = 0; r < 4; r++) acc[m * 4 + v][r] *= aR[r];
        }
      }
    }

    // O[q][v-slice of this wave] += P @ V   (af: LDS broadcast; bf: registers)
    __builtin_amdgcn_s_setprio(1);
    #pragma unroll
    for (int m = 0; m < 4; m++) {
      #pragma unroll
      for (int ks2 = 0; ks2 < 2; ks2++) {
        int cp = (ks2 * 8 + quad * 2) ^ ((l16 & 7) << 1);
        s16x8 af = *(const s16x8*)&sP[c][m][l16 * 64 + cp * 4];
        #pragma unroll
        for (int v = 0; v < 4; v++)
          acc[m * 4 + v] = mfma16(af, pv[v * 2 + ks2], acc[m * 4 + v]);
      }
    }
    __builtin_amdgcn_s_setprio(0);

    // stream next V tile into registers (consumed after next barrier)
    if (kt + 1 < 32) loadV();
    c ^= 1;
  }

  // epilogue: share l_i across waves (q-row wave*16+l16 -> all waves need it)
  if (quad == 0) sAl[0][wave * 16 + l16] = l_i;
  __syncthreads();
  #pragma unroll
  for (int m = 0; m < 4; m++) {
    f32x4 lv = *(const f32x4*)&sAl[0][m * 16 + quad * 4];
    #pragma unroll
    for (int r = 0; r < 4; r++) {
      float inv = 1.f / lv[r];
      int row = q0 + m * 16 + quad * 4 + r;
      #pragma unroll
      for (int v = 0; v < 4; v++)
        O[((size_t)(b * N_ + row)) * VD_ + wave * 64 + v * 16 + l16] =
            acc[m * 4 + v][r] * inv;
    }
  }
}

extern "C" void kernel_launch(void* const* d_in, const int* in_sizes, int n_in,
                              void* d_out, int out_size, void* d_ws, size_t ws_size,
                              hipStream_t stream) {
  const float* k1 = (const float*)d_in[0];
  const float* k2 = (const float*)d_in[1];
  const float* v1 = (const float*)d_in[2];
  const float* v2 = (const float*)d_in[3];
  const float* W1 = (const float*)d_in[4];
  const float* b1 = (const float*)d_in[5];
  const float* W2 = (const float*)d_in[6];
  const float* b2 = (const float*)d_in[7];

  short* ws  = (short*)d_ws;
  short* q1p = ws;                                   // 16384*128 f16 (4 MB)
  short* q2p = q1p + (size_t)16384 * 128;
  short* vt1 = q2p + (size_t)16384 * 128;            // 8*32*256*64 f16 (8.4 MB)
  short* vt2 = vt1 + (size_t)B_ * 32 * 256 * 64;
  float* out = (float*)d_out;

  prep_k<<<dim3(1024), dim3(256), 0, stream>>>(k1, k2, v1, v2, W1, b1, W2, b2,
                                               q1p, q2p, vt1, vt2);
  attn_k<<<dim3(512), dim3(256), 0, stream>>>(q1p, q2p, vt1, vt2, out);
}